// Round 12
// baseline (1238.217 us; speedup 1.0000x reference)
//
#include <hip/hip_runtime.h>
#include <hip/hip_bf16.h>
#include <stdint.h>

typedef __attribute__((ext_vector_type(4))) float  f32x4;
typedef __attribute__((ext_vector_type(8))) short  s16x8;
typedef __attribute__((ext_vector_type(4))) short  s16x4;

constexpr int I_SZ = 2048;
constexpr int O_SZ = 2048;
constexpr int T_SZ = 2048;
constexpr int B_MAX = 16;

constexpr size_t XT_ELEMS = (size_t)B_MAX * T_SZ * I_SZ;
constexpr size_t WT_ELEMS = (size_t)B_MAX * I_SZ * O_SZ;
constexpr size_t WS_NEEDED = (XT_ELEMS + WT_ELEMS) * sizeof(short); // 256 MB

__device__ __forceinline__ short f2bf(float f) {
    __hip_bfloat16 h = __float2bfloat16(f);
    return *reinterpret_cast<short*>(&h);
}

__device__ __forceinline__ void gload_lds16(const void* g, void* l) {
    __builtin_amdgcn_global_load_lds(
        (const __attribute__((address_space(1))) unsigned int*)g,
        (__attribute__((address_space(3))) unsigned int*)l, 16, 0, 0);
}

// keep a value live without cost (rule 17: ablation-via-skip DCEs upstream ops)
__device__ __forceinline__ void keep(s16x8& x) {
    asm volatile("" : "+v"(x));
}

// ---------------- conversion: x fp32 [B][T][I] -> pre-tiled bf16 ----------------
__global__ __launch_bounds__(256) void convA(const float* __restrict__ x,
                                             short* __restrict__ xt) {
    const int c = blockIdx.x * 256 + threadIdx.x;
    const int l  = c & 63;
    const int mi = (c >> 6) & 7;
    const int kt = (c >> 9) & 63;
    const int rest = c >> 15;
    const int mt = rest & 15, bz = rest >> 4;
    const int lr = l & 15, hi = l >> 4;
    const int m = mt * 128 + mi * 16 + lr;
    const float* src = x + ((size_t)(bz * T_SZ + m)) * I_SZ + kt * 32 + 4 * hi;
    f32x4 a = *reinterpret_cast<const f32x4*>(src);
    f32x4 b = *reinterpret_cast<const f32x4*>(src + 16);
    s16x8 h = { f2bf(a[0]), f2bf(a[1]), f2bf(a[2]), f2bf(a[3]),
                f2bf(b[0]), f2bf(b[1]), f2bf(b[2]), f2bf(b[3]) };
    *reinterpret_cast<s16x8*>(xt + (size_t)c * 8) = h;
}

__global__ __launch_bounds__(256) void convB(const float* __restrict__ fcw,
                                             const int* __restrict__ dom_id,
                                             short* __restrict__ wt) {
    const int c = blockIdx.x * 256 + threadIdx.x;
    const int l  = c & 63;
    const int ni = (c >> 6) & 7;
    const int kt = (c >> 9) & 63;
    const int rest = c >> 15;
    const int nt = rest & 15, bz = rest >> 4;
    const int lr = l & 15, hi = l >> 4;
    const int n = nt * 128 + ni * 16 + lr;
    const int dom = dom_id[bz];
    const float* src = fcw + (size_t)dom * ((size_t)I_SZ * O_SZ)
                           + (size_t)(kt * 32 + 4 * hi) * O_SZ + n;
    short h[8];
    #pragma unroll
    for (int j = 0; j < 4; ++j) {
        h[j]     = f2bf(src[(size_t)j * O_SZ]);
        h[4 + j] = f2bf(src[(size_t)(16 + j) * O_SZ]);
    }
    *reinterpret_cast<s16x8*>(wt + (size_t)c * 8) =
        *reinterpret_cast<s16x8*>(h);
}

// ======== ABLATION: R6 structure, template-gated components ========
// MODE 0: full (real result).       MODE 1: no MFMA (reads kept live).
// MODE 2: no in-loop ds_reads (persistent frags).  MODE 3: no stage/vmcnt in loop.
// All modes: full 16-bz work, identical grid/barriers; modes 1-3 write garbage
// to d_out and are dispatched BEFORE mode 0, which overwrites every element.
template<int MODE>
__global__ __launch_bounds__(512, 2) void gemm_abl(
        const short* __restrict__ xt, const short* __restrict__ wt,
        const float* __restrict__ bw, const int* __restrict__ dom_id,
        float* __restrict__ out) {
    __shared__ short As[4][8192];
    __shared__ short Bs[4][8192];

    const int bid = blockIdx.x;
    const int swz = (bid & 7) * 128 + (bid >> 3);
    const int bz = swz >> 6;
    const int mb = (swz >> 3) & 7;
    const int nb = swz & 7;

    const short* Abase = xt + (size_t)(bz * 16 + mb * 2) * 64 * 4096;
    const short* Bbase = wt + (size_t)(bz * 16 + nb * 2) * 64 * 4096;

    const int t = threadIdx.x;
    const int wv = t >> 6, l = t & 63;
    const int wm = wv >> 2, wn = wv & 3;
    const int lr = l & 15, hi = l >> 4;
    const int bni = wn >> 1, bsub = (wn & 1) * 4;

    auto stageA = [&](int buf, int kt) {
        #pragma unroll
        for (int i = 0; i < 2; ++i) {
            const int c = wv * 2 + i;
            const int mi = c >> 3, inner = c & 7;
            gload_lds16(Abase + (size_t)(mi * 64 + kt) * 4096 + inner * 512 + l * 8,
                        &As[buf][c * 512]);
        }
    };
    auto stageB = [&](int buf, int kt) {
        #pragma unroll
        for (int i = 0; i < 2; ++i) {
            const int c = wv * 2 + i;
            const int ni = c >> 3, inner = c & 7;
            gload_lds16(Bbase + (size_t)(ni * 64 + kt) * 4096 + inner * 512 + l * 8,
                        &Bs[buf][c * 512]);
        }
    };

    f32x4 acc[8][4] = {};
    s16x8 paf[8], pbq[4];   // persistent frags for MODE 2

    // prologue: 3 stage-pairs in flight (identical for all modes)
    stageA(0, 0); stageB(0, 0);
    stageA(1, 1); stageB(1, 1);
    stageA(2, 2); stageB(2, 2);
    if constexpr (MODE == 2 || MODE == 3) {
        // MODE2: capture frags once. MODE3: drain everything (no in-loop vmcnt).
        asm volatile("s_waitcnt vmcnt(0)" ::: "memory");
        asm volatile("s_barrier" ::: "memory");
        #pragma unroll
        for (int g = 0; g < 4; ++g)
            pbq[g] = *reinterpret_cast<const s16x8*>(
                         &Bs[0][bni * 4096 + (bsub + g) * 512 + l * 8]);
        #pragma unroll
        for (int f = 0; f < 8; ++f)
            paf[f] = *reinterpret_cast<const s16x8*>(
                         &As[0][wm * 4096 + f * 512 + l * 8]);
    }

    for (int kt = 0; kt < 64; ++kt) {
        const int cur = kt & 3;
        const int pre = (kt + 3) & 3;
        const int pkt = (kt + 3 > 63) ? 63 : kt + 3;

        if constexpr (MODE != 3)
            asm volatile("s_waitcnt vmcnt(8)" ::: "memory");
        asm volatile("s_barrier" ::: "memory");        // BAR-a

        s16x8 af[4], bq[4], af2[4];
        if constexpr (MODE != 2) {
            #pragma unroll
            for (int g = 0; g < 4; ++g)
                bq[g] = *reinterpret_cast<const s16x8*>(
                            &Bs[cur][bni * 4096 + (bsub + g) * 512 + l * 8]);
            #pragma unroll
            for (int f = 0; f < 4; ++f)
                af[f] = *reinterpret_cast<const s16x8*>(
                            &As[cur][wm * 4096 + f * 512 + l * 8]);
        }
        if constexpr (MODE != 3) stageA(pre, pkt);
        asm volatile("s_barrier" ::: "memory");        // BAR-b

        __builtin_amdgcn_s_setprio(1);
        if constexpr (MODE == 1) {
            #pragma unroll
            for (int g = 0; g < 4; ++g) keep(bq[g]);
            #pragma unroll
            for (int f = 0; f < 4; ++f) keep(af[f]);
        } else {
            const s16x8* A0 = (MODE == 2) ? paf : af;
            const s16x8* B0 = (MODE == 2) ? pbq : bq;
            #pragma unroll
            for (int f = 0; f < 4; ++f)
                #pragma unroll
                for (int g = 0; g < 4; ++g)
                    acc[f][g] = __builtin_amdgcn_mfma_f32_16x16x32_bf16(
                                    A0[f], B0[g], acc[f][g], 0, 0, 0);
        }
        __builtin_amdgcn_s_setprio(0);

        if constexpr (MODE != 2) {
            #pragma unroll
            for (int f = 0; f < 4; ++f)
                af2[f] = *reinterpret_cast<const s16x8*>(
                            &As[cur][wm * 4096 + (4 + f) * 512 + l * 8]);
        }
        if constexpr (MODE != 3) stageB(pre, pkt);
        asm volatile("s_barrier" ::: "memory");        // BAR-c

        __builtin_amdgcn_s_setprio(1);
        if constexpr (MODE == 1) {
            #pragma unroll
            for (int f = 0; f < 4; ++f) keep(af2[f]);
        } else {
            const s16x8* A1 = (MODE == 2) ? (paf + 4) : af2;
            const s16x8* B1 = (MODE == 2) ? pbq : bq;
            #pragma unroll
            for (int f = 0; f < 4; ++f)
                #pragma unroll
                for (int g = 0; g < 4; ++g)
                    acc[4 + f][g] = __builtin_amdgcn_mfma_f32_16x16x32_bf16(
                                        A1[f], B1[g], acc[4 + f][g], 0, 0, 0);
        }
        __builtin_amdgcn_s_setprio(0);
    }

    asm volatile("s_waitcnt vmcnt(0)" ::: "memory");

    const int dom = dom_id[bz];
    const int col0 = nb * 256 + wn * 64;
    float bias[4];
    #pragma unroll
    for (int g = 0; g < 4; ++g)
        bias[g] = bw[dom * O_SZ + col0 + g * 16 + lr];

    const size_t obase = ((size_t)bz * T_SZ + mb * 256 + wm * 128) * O_SZ + col0;
    #pragma unroll
    for (int f = 0; f < 8; ++f) {
        #pragma unroll
        for (int r = 0; r < 4; ++r) {
            const int row = f * 16 + hi * 4 + r;
            float* orow = out + obase + (size_t)row * O_SZ;
            #pragma unroll
            for (int g = 0; g < 4; ++g)
                orow[g * 16 + lr] = acc[f][g][r] + bias[g];
        }
    }
}

// =============== fallback (round-1 kernel) if workspace is too small ===============
constexpr int BM = 128, BN = 128, BK = 32;
constexpr int LDK = 40;
constexpr int NKT = I_SZ / BK;

__global__ __launch_bounds__(256) void dal_gemm(
    const float* __restrict__ x, const int* __restrict__ dom_id,
    const float* __restrict__ fcw, const float* __restrict__ bw,
    float* __restrict__ out)
{
    __shared__ short As[2][BM * LDK];
    __shared__ short Bs[2][BN * LDK];
    const int bz = blockIdx.z;
    const int m0 = blockIdx.y * BM, n0 = blockIdx.x * BN;
    const int dom = dom_id[bz];
    const float* Ag = x + ((size_t)bz * T_SZ + m0) * I_SZ;
    const float* Wg = fcw + (size_t)dom * ((size_t)I_SZ * O_SZ) + n0;
    const int t = threadIdx.x;
    const int am = t >> 3, ac = (t & 7) << 2;
    const int bk = (t >> 5) << 2, bn = (t & 31) << 2;
    const int wv = t >> 6, lane = t & 63;
    const int wr = (wv >> 1) << 6, wc = (wv & 1) << 6;
    const int hi = lane >> 4, lr = lane & 15;
    f32x4 acc[4][4] = {};
    f32x4 ra[4], rb[4];
    auto load_tile = [&](int kb) {
        #pragma unroll
        for (int p = 0; p < 4; ++p)
            ra[p] = *reinterpret_cast<const f32x4*>(Ag + (size_t)(am + 32 * p) * I_SZ + kb + ac);
        #pragma unroll
        for (int r = 0; r < 4; ++r)
            rb[r] = *reinterpret_cast<const f32x4*>(Wg + (size_t)(kb + bk + r) * O_SZ + bn);
    };
    auto store_tile = [&](int buf) {
        #pragma unroll
        for (int p = 0; p < 4; ++p) {
            s16x4 h = { f2bf(ra[p][0]), f2bf(ra[p][1]), f2bf(ra[p][2]), f2bf(ra[p][3]) };
            *reinterpret_cast<s16x4*>(&As[buf][(am + 32 * p) * LDK + ac]) = h;
        }
        #pragma unroll
        for (int i = 0; i < 4; ++i) {
            s16x4 h = { f2bf(rb[0][i]), f2bf(rb[1][i]), f2bf(rb[2][i]), f2bf(rb[3][i]) };
            *reinterpret_cast<s16x4*>(&Bs[buf][(bn + i) * LDK + bk]) = h;
        }
    };
    load_tile(0);
    store_tile(0);
    __syncthreads();
    for (int kt = 0; kt < NKT; ++kt) {
        const int cur = kt & 1;
        if (kt + 1 < NKT) load_tile((kt + 1) * BK);
        s16x8 af[4], bfr[4];
        #pragma unroll
        for (int im = 0; im < 4; ++im) {
            const short* p = &As[cur][(wr + im * 16 + lr) * LDK + 4 * hi];
            s16x4 lo = *reinterpret_cast<const s16x4*>(p);
            s16x4 hh = *reinterpret_cast<const s16x4*>(p + 16);
            af[im] = __builtin_shufflevector(lo, hh, 0, 1, 2, 3, 4, 5, 6, 7);
        }
        #pragma unroll
        for (int in = 0; in < 4; ++in) {
            const short* p = &Bs[cur][(wc + in * 16 + lr) * LDK + 4 * hi];
            s16x4 lo = *reinterpret_cast<const s16x4*>(p);
            s16x4 hh = *reinterpret_cast<const s16x4*>(p + 16);
            bfr[in] = __builtin_shufflevector(lo, hh, 0, 1, 2, 3, 4, 5, 6, 7);
        }
        #pragma unroll
        for (int im = 0; im < 4; ++im)
            #pragma unroll
            for (int in = 0; in < 4; ++in)
                acc[im][in] = __builtin_amdgcn_mfma_f32_16x16x32_bf16(
                                  af[im], bfr[in], acc[im][in], 0, 0, 0);
        if (kt + 1 < NKT) store_tile(cur ^ 1);
        __syncthreads();
    }
    float bias[4];
    #pragma unroll
    for (int in = 0; in < 4; ++in)
        bias[in] = bw[dom * O_SZ + n0 + wc + in * 16 + lr];
    const size_t obase = ((size_t)bz * T_SZ + m0) * O_SZ + n0;
    #pragma unroll
    for (int im = 0; im < 4; ++im) {
        #pragma unroll
        for (int r = 0; r < 4; ++r) {
            const int row = wr + im * 16 + hi * 4 + r;
            float* orow = out + obase + (size_t)row * O_SZ;
            #pragma unroll
            for (int in = 0; in < 4; ++in)
                orow[wc + in * 16 + lr] = acc[im][in][r] + bias[in];
        }
    }
}

extern "C" void kernel_launch(void* const* d_in, const int* in_sizes, int n_in,
                              void* d_out, int out_size, void* d_ws, size_t ws_size,
                              hipStream_t stream) {
    const float* x   = (const float*)d_in[0];
    const int*   dom = (const int*)d_in[1];
    const float* fcw = (const float*)d_in[2];
    const float* bw  = (const float*)d_in[3];
    float* out = (float*)d_out;
    const int B = in_sizes[1];   // 16

    if (ws_size >= WS_NEEDED && B == B_MAX) {
        short* xt = (short*)d_ws;
        short* wt = xt + XT_ELEMS;
        const int chunks = B * 16 * 64 * 512;
        convA<<<chunks / 256, 256, 0, stream>>>(x, xt);
        convB<<<chunks / 256, 256, 0, stream>>>(fcw, dom, wt);
        // ablation: diagnostics first (their d_out garbage is overwritten by <0>)
        gemm_abl<1><<<dim3(1024), dim3(512), 0, stream>>>(xt, wt, bw, dom, out);
        gemm_abl<2><<<dim3(1024), dim3(512), 0, stream>>>(xt, wt, bw, dom, out);
        gemm_abl<3><<<dim3(1024), dim3(512), 0, stream>>>(xt, wt, bw, dom, out);
        gemm_abl<0><<<dim3(1024), dim3(512), 0, stream>>>(xt, wt, bw, dom, out);
    } else {
        dim3 grid(O_SZ / BN, T_SZ / BM, B);
        dal_gemm<<<grid, dim3(256), 0, stream>>>(x, dom, fcw, bw, out);
    }
}

// Round 13
// 492.855 us; speedup vs baseline: 2.5123x; 2.5123x over previous
//
#include <hip/hip_runtime.h>
#include <hip/hip_bf16.h>
#include <stdint.h>

typedef __attribute__((ext_vector_type(4))) float  f32x4;
typedef __attribute__((ext_vector_type(8))) short  s16x8;
typedef __attribute__((ext_vector_type(4))) short  s16x4;

constexpr int I_SZ = 2048;
constexpr int O_SZ = 2048;
constexpr int T_SZ = 2048;
constexpr int B_MAX = 16;

// pre-tiled layout: per (bz, tile128, ktile32): 8KB block = 8 subtiles x 1KB;
// within a subtile, byte offset l*16 holds the MFMA fragment of lane l:
// row = l&15, k = 4*(l>>4) + {0..3} and 16 + 4*(l>>4) + {0..3}
constexpr size_t XT_ELEMS = (size_t)B_MAX * T_SZ * I_SZ;
constexpr size_t WT_ELEMS = (size_t)B_MAX * I_SZ * O_SZ;
constexpr size_t WS_NEEDED = (XT_ELEMS + WT_ELEMS) * sizeof(short); // 256 MB

__device__ __forceinline__ short f2bf(float f) {
    __hip_bfloat16 h = __float2bfloat16(f);
    return *reinterpret_cast<short*>(&h);
}

__device__ __forceinline__ void gload_lds16(const void* g, void* l) {
    __builtin_amdgcn_global_load_lds(
        (const __attribute__((address_space(1))) unsigned int*)g,
        (__attribute__((address_space(3))) unsigned int*)l, 16, 0, 0);
}

// ---------------- conversion: x fp32 [B][T][I] -> pre-tiled bf16 ----------------
__global__ __launch_bounds__(256) void convA(const float* __restrict__ x,
                                             short* __restrict__ xt) {
    const int c = blockIdx.x * 256 + threadIdx.x;
    const int l  = c & 63;
    const int mi = (c >> 6) & 7;
    const int kt = (c >> 9) & 63;
    const int rest = c >> 15;
    const int mt = rest & 15, bz = rest >> 4;
    const int lr = l & 15, hi = l >> 4;
    const int m = mt * 128 + mi * 16 + lr;
    const float* src = x + ((size_t)(bz * T_SZ + m)) * I_SZ + kt * 32 + 4 * hi;
    f32x4 a = *reinterpret_cast<const f32x4*>(src);
    f32x4 b = *reinterpret_cast<const f32x4*>(src + 16);
    s16x8 h = { f2bf(a[0]), f2bf(a[1]), f2bf(a[2]), f2bf(a[3]),
                f2bf(b[0]), f2bf(b[1]), f2bf(b[2]), f2bf(b[3]) };
    *reinterpret_cast<s16x8*>(xt + (size_t)c * 8) = h;
}

__global__ __launch_bounds__(256) void convB(const float* __restrict__ fcw,
                                             const int* __restrict__ dom_id,
                                             short* __restrict__ wt) {
    const int c = blockIdx.x * 256 + threadIdx.x;
    const int l  = c & 63;
    const int ni = (c >> 6) & 7;
    const int kt = (c >> 9) & 63;
    const int rest = c >> 15;
    const int nt = rest & 15, bz = rest >> 4;
    const int lr = l & 15, hi = l >> 4;
    const int n = nt * 128 + ni * 16 + lr;
    const int dom = dom_id[bz];
    const float* src = fcw + (size_t)dom * ((size_t)I_SZ * O_SZ)
                           + (size_t)(kt * 32 + 4 * hi) * O_SZ + n;
    short h[8];
    #pragma unroll
    for (int j = 0; j < 4; ++j) {
        h[j]     = f2bf(src[(size_t)j * O_SZ]);
        h[4 + j] = f2bf(src[(size_t)(16 + j) * O_SZ]);
    }
    *reinterpret_cast<s16x8*>(wt + (size_t)c * 8) =
        *reinterpret_cast<s16x8*>(h);
}

// ---- bf16 GEMM, 256x256 tile, A via LDS (BK=64 bursts), B direct-to-register ----
// Serial-sum diagnosis (R12 ablation): stage-wait ~1200 + ds_read ~1150 + MFMA
// ~1240 cyc run in SERIES per K32 at 1 block/CU lockstep. Fixes here:
//  (1) B frags load global->VGPR (coalesced 1KB/wave, pre-tiled ws) - off the
//      barrier'd path entirely; consumed mid-iter via compiler register waits.
//  (2) A staged in 32KB K64 bursts, ring-2 (64KB LDS): half as many
//      vmcnt(0)+barrier points, ~2x compute under each stage.
//  (3) bq loads issue BEFORE stageA each iter (vmcnt FIFO is in-order: waiting
//      on bq must not force-drain the A-stage).
// Per K64 iter: [bq(T) 8 gloads; stageA(T+1) 4 gload_lds; af-k0 8 ds_read;
//               32 MFMA; af-k1 8 ds_read; 32 MFMA; vmcnt(0); barrier]
__global__ __launch_bounds__(512, 2) void gemm_bdir(
        const short* __restrict__ xt, const short* __restrict__ wt,
        const float* __restrict__ bw, const int* __restrict__ dom_id,
        float* __restrict__ out) {
    __shared__ short As[2][16384];   // 2 bufs x 32KB: [ks*2+mi][frag*512+l*8]

    // bijective XCD swizzle: nwg = 1024 = 8 XCDs x 128
    const int bid = blockIdx.x;
    const int swz = (bid & 7) * 128 + (bid >> 3);
    const int bz = swz >> 6;
    const int mb = (swz >> 3) & 7;   // 256-row tile index
    const int nb = swz & 7;          // 256-col tile index

    const int t = threadIdx.x;
    const int wv = t >> 6, l = t & 63;
    const int wm = wv >> 2, wn = wv & 3;
    const int lr = l & 15, hi = l >> 4;
    const int bni = wn >> 1, bsub = (wn & 1) * 4;

    const short* Abase = xt + (size_t)(bz * 16 + mb * 2) * 64 * 4096;
    // per-lane B fragment base: frag (ks,g) of tile T at +(2T+ks)*4096 + g*512
    const short* Bp = wt + (size_t)((bz * 16 + nb * 2 + bni) * 64) * 4096
                         + bsub * 512 + l * 8;

    // stage one K64 A-burst (32KB) into buf: round r = ks*2+mi, linear 8KB copies
    auto stageA = [&](int buf, int T) {
        #pragma unroll
        for (int r = 0; r < 4; ++r) {
            const int mi = r & 1, ks = r >> 1;
            gload_lds16(Abase + ((size_t)(mi * 64 + 2 * T + ks)) * 4096 + t * 8,
                        &As[buf][r * 4096 + t * 8]);
        }
    };

    f32x4 acc[8][4] = {};

    stageA(0, 0);
    asm volatile("s_waitcnt vmcnt(0)" ::: "memory");
    asm volatile("s_barrier" ::: "memory");

    for (int T = 0; T < 32; ++T) {
        const int d = T & 1;

        // (3) B frags FIRST in the FIFO: 8 coalesced 16B/lane loads for this tile
        s16x8 bq0[4], bq1[4];
        {
            const short* b0 = Bp + (size_t)(2 * T) * 4096;
            const short* b1 = b0 + 4096;
            #pragma unroll
            for (int g = 0; g < 4; ++g) bq0[g] = *reinterpret_cast<const s16x8*>(b0 + g * 512);
            #pragma unroll
            for (int g = 0; g < 4; ++g) bq1[g] = *reinterpret_cast<const s16x8*>(b1 + g * 512);
        }

        // (2) A-stage for next tile issues now; drains at end-of-iter vmcnt(0)
        if (T + 1 < 32) stageA(d ^ 1, T + 1);

        // ks = 0: 8 af reads + 32 MFMA
        s16x8 af[8];
        #pragma unroll
        for (int f = 0; f < 8; ++f)
            af[f] = *reinterpret_cast<const s16x8*>(
                        &As[d][(0 * 2 + wm) * 4096 + f * 512 + l * 8]);
        __builtin_amdgcn_s_setprio(1);
        #pragma unroll
        for (int f = 0; f < 8; ++f)
            #pragma unroll
            for (int g = 0; g < 4; ++g)
                acc[f][g] = __builtin_amdgcn_mfma_f32_16x16x32_bf16(
                                af[f], bq0[g], acc[f][g], 0, 0, 0);
        __builtin_amdgcn_s_setprio(0);

        // ks = 1
        #pragma unroll
        for (int f = 0; f < 8; ++f)
            af[f] = *reinterpret_cast<const s16x8*>(
                        &As[d][(1 * 2 + wm) * 4096 + f * 512 + l * 8]);
        __builtin_amdgcn_s_setprio(1);
        #pragma unroll
        for (int f = 0; f < 8; ++f)
            #pragma unroll
            for (int g = 0; g < 4; ++g)
                acc[f][g] = __builtin_amdgcn_mfma_f32_16x16x32_bf16(
                                af[f], bq1[g], acc[f][g], 0, 0, 0);
        __builtin_amdgcn_s_setprio(0);

        // release: next tile's A fully landed, all reads of buf d retired
        asm volatile("s_waitcnt vmcnt(0)" ::: "memory");
        asm volatile("s_barrier" ::: "memory");
    }

    // epilogue: bias + store (wave tile: rows wm*128..+128, cols wn*64..+64)
    const int dom = dom_id[bz];
    const int col0 = nb * 256 + wn * 64;
    float bias[4];
    #pragma unroll
    for (int g = 0; g < 4; ++g)
        bias[g] = bw[dom * O_SZ + col0 + g * 16 + lr];

    const size_t obase = ((size_t)bz * T_SZ + mb * 256 + wm * 128) * O_SZ + col0;
    #pragma unroll
    for (int f = 0; f < 8; ++f) {
        #pragma unroll
        for (int r = 0; r < 4; ++r) {
            const int row = f * 16 + hi * 4 + r;
            float* orow = out + obase + (size_t)row * O_SZ;
            #pragma unroll
            for (int g = 0; g < 4; ++g)
                orow[g * 16 + lr] = acc[f][g][r] + bias[g];
        }
    }
}

// =============== fallback (round-1 kernel) if workspace is too small ===============
constexpr int BM = 128, BN = 128, BK = 32;
constexpr int LDK = 40;
constexpr int NKT = I_SZ / BK;

__global__ __launch_bounds__(256) void dal_gemm(
    const float* __restrict__ x, const int* __restrict__ dom_id,
    const float* __restrict__ fcw, const float* __restrict__ bw,
    float* __restrict__ out)
{
    __shared__ short As[2][BM * LDK];
    __shared__ short Bs[2][BN * LDK];
    const int bz = blockIdx.z;
    const int m0 = blockIdx.y * BM, n0 = blockIdx.x * BN;
    const int dom = dom_id[bz];
    const float* Ag = x + ((size_t)bz * T_SZ + m0) * I_SZ;
    const float* Wg = fcw + (size_t)dom * ((size_t)I_SZ * O_SZ) + n0;
    const int t = threadIdx.x;
    const int am = t >> 3, ac = (t & 7) << 2;
    const int bk = (t >> 5) << 2, bn = (t & 31) << 2;
    const int wv = t >> 6, lane = t & 63;
    const int wr = (wv >> 1) << 6, wc = (wv & 1) << 6;
    const int hi = lane >> 4, lr = lane & 15;
    f32x4 acc[4][4] = {};
    f32x4 ra[4], rb[4];
    auto load_tile = [&](int kb) {
        #pragma unroll
        for (int p = 0; p < 4; ++p)
            ra[p] = *reinterpret_cast<const f32x4*>(Ag + (size_t)(am + 32 * p) * I_SZ + kb + ac);
        #pragma unroll
        for (int r = 0; r < 4; ++r)
            rb[r] = *reinterpret_cast<const f32x4*>(Wg + (size_t)(kb + bk + r) * O_SZ + bn);
    };
    auto store_tile = [&](int buf) {
        #pragma unroll
        for (int p = 0; p < 4; ++p) {
            s16x4 h = { f2bf(ra[p][0]), f2bf(ra[p][1]), f2bf(ra[p][2]), f2bf(ra[p][3]) };
            *reinterpret_cast<s16x4*>(&As[buf][(am + 32 * p) * LDK + ac]) = h;
        }
        #pragma unroll
        for (int i = 0; i < 4; ++i) {
            s16x4 h = { f2bf(rb[0][i]), f2bf(rb[1][i]), f2bf(rb[2][i]), f2bf(rb[3][i]) };
            *reinterpret_cast<s16x4*>(&Bs[buf][(bn + i) * LDK + bk]) = h;
        }
    };
    load_tile(0);
    store_tile(0);
    __syncthreads();
    for (int kt = 0; kt < NKT; ++kt) {
        const int cur = kt & 1;
        if (kt + 1 < NKT) load_tile((kt + 1) * BK);
        s16x8 af[4], bfr[4];
        #pragma unroll
        for (int im = 0; im < 4; ++im) {
            const short* p = &As[cur][(wr + im * 16 + lr) * LDK + 4 * hi];
            s16x4 lo = *reinterpret_cast<const s16x4*>(p);
            s16x4 hh = *reinterpret_cast<const s16x4*>(p + 16);
            af[im] = __builtin_shufflevector(lo, hh, 0, 1, 2, 3, 4, 5, 6, 7);
        }
        #pragma unroll
        for (int in = 0; in < 4; ++in) {
            const short* p = &Bs[cur][(wc + in * 16 + lr) * LDK + 4 * hi];
            s16x4 lo = *reinterpret_cast<const s16x4*>(p);
            s16x4 hh = *reinterpret_cast<const s16x4*>(p + 16);
            bfr[in] = __builtin_shufflevector(lo, hh, 0, 1, 2, 3, 4, 5, 6, 7);
        }
        #pragma unroll
        for (int im = 0; im < 4; ++im)
            #pragma unroll
            for (int in = 0; in < 4; ++in)
                acc[im][in] = __builtin_amdgcn_mfma_f32_16x16x32_bf16(
                                  af[im], bfr[in], acc[im][in], 0, 0, 0);
        if (kt + 1 < NKT) store_tile(cur ^ 1);
        __syncthreads();
    }
    float bias[4];
    #pragma unroll
    for (int in = 0; in < 4; ++in)
        bias[in] = bw[dom * O_SZ + n0 + wc + in * 16 + lr];
    const size_t obase = ((size_t)bz * T_SZ + m0) * O_SZ + n0;
    #pragma unroll
    for (int im = 0; im < 4; ++im) {
        #pragma unroll
        for (int r = 0; r < 4; ++r) {
            const int row = wr + im * 16 + hi * 4 + r;
            float* orow = out + obase + (size_t)row * O_SZ;
            #pragma unroll
            for (int in = 0; in < 4; ++in)
                orow[wc + in * 16 + lr] = acc[im][in][r] + bias[in];
        }
    }
}

extern "C" void kernel_launch(void* const* d_in, const int* in_sizes, int n_in,
                              void* d_out, int out_size, void* d_ws, size_t ws_size,
                              hipStream_t stream) {
    const float* x   = (const float*)d_in[0];
    const int*   dom = (const int*)d_in[1];
    const float* fcw = (const float*)d_in[2];
    const float* bw  = (const float*)d_in[3];
    float* out = (float*)d_out;
    const int B = in_sizes[1];   // 16

    if (ws_size >= WS_NEEDED && B == B_MAX) {
        short* xt = (short*)d_ws;
        short* wt = xt + XT_ELEMS;
        const int chunks = B * 16 * 64 * 512;
        convA<<<chunks / 256, 256, 0, stream>>>(x, xt);
        convB<<<chunks / 256, 256, 0, stream>>>(fcw, dom, wt);
        gemm_bdir<<<dim3(1024), dim3(512), 0, stream>>>(xt, wt, bw, dom, out);
    } else {
        dim3 grid(O_SZ / BN, T_SZ / BM, B);
        dal_gemm<<<grid, dim3(256), 0, stream>>>(x, dom, fcw, bw, out);
    }
}

// Round 14
// 417.957 us; speedup vs baseline: 2.9626x; 1.1792x over previous
//
#include <hip/hip_runtime.h>
#include <hip/hip_bf16.h>
#include <stdint.h>

typedef __attribute__((ext_vector_type(4))) float  f32x4;
typedef __attribute__((ext_vector_type(8))) short  s16x8;
typedef __attribute__((ext_vector_type(4))) short  s16x4;

constexpr int I_SZ = 2048;
constexpr int O_SZ = 2048;
constexpr int T_SZ = 2048;
constexpr int B_MAX = 16;

// pre-tiled layout: per (bz, tile128, ktile32): 8KB block = 8 subtiles x 1KB;
// within a subtile, byte offset l*16 holds the MFMA fragment of lane l:
// row = l&15, k = 4*(l>>4) + {0..3} and 16 + 4*(l>>4) + {0..3}
constexpr size_t XT_ELEMS = (size_t)B_MAX * T_SZ * I_SZ;
constexpr size_t WT_ELEMS = (size_t)B_MAX * I_SZ * O_SZ;
constexpr size_t WS_NEEDED = (XT_ELEMS + WT_ELEMS) * sizeof(short); // 256 MB

__device__ __forceinline__ short f2bf(float f) {
    __hip_bfloat16 h = __float2bfloat16(f);
    return *reinterpret_cast<short*>(&h);
}

__device__ __forceinline__ void gload_lds16(const void* g, void* l) {
    __builtin_amdgcn_global_load_lds(
        (const __attribute__((address_space(1))) unsigned int*)g,
        (__attribute__((address_space(3))) unsigned int*)l, 16, 0, 0);
}

// ---------------- conversion: x fp32 [B][T][I] -> pre-tiled bf16 ----------------
__global__ __launch_bounds__(256) void convA(const float* __restrict__ x,
                                             short* __restrict__ xt) {
    const int c = blockIdx.x * 256 + threadIdx.x;
    const int l  = c & 63;
    const int mi = (c >> 6) & 7;
    const int kt = (c >> 9) & 63;
    const int rest = c >> 15;
    const int mt = rest & 15, bz = rest >> 4;
    const int lr = l & 15, hi = l >> 4;
    const int m = mt * 128 + mi * 16 + lr;
    const float* src = x + ((size_t)(bz * T_SZ + m)) * I_SZ + kt * 32 + 4 * hi;
    f32x4 a = *reinterpret_cast<const f32x4*>(src);
    f32x4 b = *reinterpret_cast<const f32x4*>(src + 16);
    s16x8 h = { f2bf(a[0]), f2bf(a[1]), f2bf(a[2]), f2bf(a[3]),
                f2bf(b[0]), f2bf(b[1]), f2bf(b[2]), f2bf(b[3]) };
    *reinterpret_cast<s16x8*>(xt + (size_t)c * 8) = h;
}

__global__ __launch_bounds__(256) void convB(const float* __restrict__ fcw,
                                             const int* __restrict__ dom_id,
                                             short* __restrict__ wt) {
    const int c = blockIdx.x * 256 + threadIdx.x;
    const int l  = c & 63;
    const int ni = (c >> 6) & 7;
    const int kt = (c >> 9) & 63;
    const int rest = c >> 15;
    const int nt = rest & 15, bz = rest >> 4;
    const int lr = l & 15, hi = l >> 4;
    const int n = nt * 128 + ni * 16 + lr;
    const int dom = dom_id[bz];
    const float* src = fcw + (size_t)dom * ((size_t)I_SZ * O_SZ)
                           + (size_t)(kt * 32 + 4 * hi) * O_SZ + n;
    short h[8];
    #pragma unroll
    for (int j = 0; j < 4; ++j) {
        h[j]     = f2bf(src[(size_t)j * O_SZ]);
        h[4 + j] = f2bf(src[(size_t)(16 + j) * O_SZ]);
    }
    *reinterpret_cast<s16x8*>(wt + (size_t)c * 8) =
        *reinterpret_cast<s16x8*>(h);
}

// ---- bf16 GEMM, 128x256 tile, 256 thr / 4 waves, 2 blocks/CU co-resident ----
// R13 post-mortem: 256^2 + 8 waves = 232 regs/wave (128 AGPR acc + 104 VGPR)
// -> exactly 1 block/CU -> lockstep serial phases, 14 B/cyc delivery.
// This tile: per wave 128x64 (acc[8][4]=128 AGPR + ~100 VGPR = 228) -> 8 waves
// = 2 INDEPENDENT blocks/CU; each block's drain is covered by the other's
// compute (m97 mechanism, now without R10's spill).
// Traffic/K64: A 16KB staged (contiguous burst, ring-2 32KB LDS) + B 32KB
// direct-to-reg, zero duplication (each B frag owned by exactly one wave)
// = 0.0114 B/FLOP, same economics as 256^2.
__global__ __launch_bounds__(256, 2) void gemm_128x256(
        const short* __restrict__ xt, const short* __restrict__ wt,
        const float* __restrict__ bw, const int* __restrict__ dom_id,
        float* __restrict__ out) {
    __shared__ short As[2][8192];   // ring-2 x 16KB (one K64 A-burst, pre-tiled)

    // bijective XCD swizzle: nwg = 2048 = 8 XCDs x 256
    const int bid = blockIdx.x;
    const int swz = (bid & 7) * 256 + (bid >> 3);
    const int bz = swz >> 7;         // 128 blocks per bz
    const int mb = (swz >> 3) & 15;  // 128-row tile index (A panel shared by 8 nb)
    const int nb = swz & 7;          // 256-col tile index

    const int t = threadIdx.x;
    const int wv = t >> 6, l = t & 63;
    const int lr = l & 15, hi = l >> 4;
    const int nti  = wv >> 1;        // which 128-col sub-tile of the 256 N-tile
    const int bsub = (wv & 1) * 4;   // which 4-subtile half within it

    // A: kt is innermost in the pre-tiled layout -> a K64 burst is 16KB contiguous
    const short* Abase = xt + (size_t)(bz * 16 + mb) * 64 * 4096;
    // per-lane B fragment base (this wave's exclusive column quarter)
    const short* Bp = wt + (size_t)((bz * 16 + nb * 2 + nti) * 64) * 4096
                         + bsub * 512 + l * 8;

    auto stageA = [&](int buf, int T) {
        #pragma unroll
        for (int r = 0; r < 4; ++r)   // 4 x 4KB rounds (256 thr x 16B), lane-linear
            gload_lds16(Abase + (size_t)(2 * T) * 4096 + r * 2048 + t * 8,
                        &As[buf][r * 2048 + t * 8]);
    };

    f32x4 acc[8][4] = {};

    stageA(0, 0);
    asm volatile("s_waitcnt vmcnt(0)" ::: "memory");
    asm volatile("s_barrier" ::: "memory");

    for (int T = 0; T < 32; ++T) {
        const int d = T & 1;

        // B frags FIRST in the vmcnt FIFO (waiting on them must not drain the stage)
        s16x8 bq0[4], bq1[4];
        {
            const short* b0 = Bp + (size_t)(2 * T) * 4096;
            #pragma unroll
            for (int g = 0; g < 4; ++g)
                bq0[g] = *reinterpret_cast<const s16x8*>(b0 + g * 512);
            #pragma unroll
            for (int g = 0; g < 4; ++g)
                bq1[g] = *reinterpret_cast<const s16x8*>(b0 + 4096 + g * 512);
        }

        // next K64 A-burst; drains at end-of-iter vmcnt(0) under this iter's MFMAs
        if (T + 1 < 32) stageA(d ^ 1, T + 1);

        // ks = 0
        s16x8 af[8];
        #pragma unroll
        for (int f = 0; f < 8; ++f)
            af[f] = *reinterpret_cast<const s16x8*>(&As[d][f * 512 + l * 8]);
        __builtin_amdgcn_s_setprio(1);
        #pragma unroll
        for (int f = 0; f < 8; ++f)
            #pragma unroll
            for (int g = 0; g < 4; ++g)
                acc[f][g] = __builtin_amdgcn_mfma_f32_16x16x32_bf16(
                                af[f], bq0[g], acc[f][g], 0, 0, 0);
        __builtin_amdgcn_s_setprio(0);

        // ks = 1
        #pragma unroll
        for (int f = 0; f < 8; ++f)
            af[f] = *reinterpret_cast<const s16x8*>(&As[d][4096 + f * 512 + l * 8]);
        __builtin_amdgcn_s_setprio(1);
        #pragma unroll
        for (int f = 0; f < 8; ++f)
            #pragma unroll
            for (int g = 0; g < 4; ++g)
                acc[f][g] = __builtin_amdgcn_mfma_f32_16x16x32_bf16(
                                af[f], bq1[g], acc[f][g], 0, 0, 0);
        __builtin_amdgcn_s_setprio(0);

        // release: next A-burst landed; all reads of buf d retired (WAR-safe:
        // stage targets d^1, whose readers finished before the PREVIOUS barrier)
        asm volatile("s_waitcnt vmcnt(0)" ::: "memory");
        asm volatile("s_barrier" ::: "memory");
    }

    // epilogue: wave tile = rows mb*128..+128, cols nb*256 + wv*64 .. +64
    const int dom = dom_id[bz];
    const int col0 = nb * 256 + wv * 64;
    float bias[4];
    #pragma unroll
    for (int g = 0; g < 4; ++g)
        bias[g] = bw[dom * O_SZ + col0 + g * 16 + lr];

    const size_t obase = ((size_t)bz * T_SZ + mb * 128) * O_SZ + col0;
    #pragma unroll
    for (int f = 0; f < 8; ++f) {
        #pragma unroll
        for (int r = 0; r < 4; ++r) {
            const int row = f * 16 + hi * 4 + r;
            float* orow = out + obase + (size_t)row * O_SZ;
            #pragma unroll
            for (int g = 0; g < 4; ++g)
                orow[g * 16 + lr] = acc[f][g][r] + bias[g];
        }
    }
}

// =============== fallback (round-1 kernel) if workspace is too small ===============
constexpr int BM = 128, BN = 128, BK = 32;
constexpr int LDK = 40;
constexpr int NKT = I_SZ / BK;

__global__ __launch_bounds__(256) void dal_gemm(
    const float* __restrict__ x, const int* __restrict__ dom_id,
    const float* __restrict__ fcw, const float* __restrict__ bw,
    float* __restrict__ out)
{
    __shared__ short As[2][BM * LDK];
    __shared__ short Bs[2][BN * LDK];
    const int bz = blockIdx.z;
    const int m0 = blockIdx.y * BM, n0 = blockIdx.x * BN;
    const int dom = dom_id[bz];
    const float* Ag = x + ((size_t)bz * T_SZ + m0) * I_SZ;
    const float* Wg = fcw + (size_t)dom * ((size_t)I_SZ * O_SZ) + n0;
    const int t = threadIdx.x;
    const int am = t >> 3, ac = (t & 7) << 2;
    const int bk = (t >> 5) << 2, bn = (t & 31) << 2;
    const int wv = t >> 6, lane = t & 63;
    const int wr = (wv >> 1) << 6, wc = (wv & 1) << 6;
    const int hi = lane >> 4, lr = lane & 15;
    f32x4 acc[4][4] = {};
    f32x4 ra[4], rb[4];
    auto load_tile = [&](int kb) {
        #pragma unroll
        for (int p = 0; p < 4; ++p)
            ra[p] = *reinterpret_cast<const f32x4*>(Ag + (size_t)(am + 32 * p) * I_SZ + kb + ac);
        #pragma unroll
        for (int r = 0; r < 4; ++r)
            rb[r] = *reinterpret_cast<const f32x4*>(Wg + (size_t)(kb + bk + r) * O_SZ + bn);
    };
    auto store_tile = [&](int buf) {
        #pragma unroll
        for (int p = 0; p < 4; ++p) {
            s16x4 h = { f2bf(ra[p][0]), f2bf(ra[p][1]), f2bf(ra[p][2]), f2bf(ra[p][3]) };
            *reinterpret_cast<s16x4*>(&As[buf][(am + 32 * p) * LDK + ac]) = h;
        }
        #pragma unroll
        for (int i = 0; i < 4; ++i) {
            s16x4 h = { f2bf(rb[0][i]), f2bf(rb[1][i]), f2bf(rb[2][i]), f2bf(rb[3][i]) };
            *reinterpret_cast<s16x4*>(&Bs[buf][(bn + i) * LDK + bk]) = h;
        }
    };
    load_tile(0);
    store_tile(0);
    __syncthreads();
    for (int kt = 0; kt < NKT; ++kt) {
        const int cur = kt & 1;
        if (kt + 1 < NKT) load_tile((kt + 1) * BK);
        s16x8 af[4], bfr[4];
        #pragma unroll
        for (int im = 0; im < 4; ++im) {
            const short* p = &As[cur][(wr + im * 16 + lr) * LDK + 4 * hi];
            s16x4 lo = *reinterpret_cast<const s16x4*>(p);
            s16x4 hh = *reinterpret_cast<const s16x4*>(p + 16);
            af[im] = __builtin_shufflevector(lo, hh, 0, 1, 2, 3, 4, 5, 6, 7);
        }
        #pragma unroll
        for (int in = 0; in < 4; ++in) {
            const short* p = &Bs[cur][(wc + in * 16 + lr) * LDK + 4 * hi];
            s16x4 lo = *reinterpret_cast<const s16x4*>(p);
            s16x4 hh = *reinterpret_cast<const s16x4*>(p + 16);
            bfr[in] = __builtin_shufflevector(lo, hh, 0, 1, 2, 3, 4, 5, 6, 7);
        }
        #pragma unroll
        for (int im = 0; im < 4; ++im)
            #pragma unroll
            for (int in = 0; in < 4; ++in)
                acc[im][in] = __builtin_amdgcn_mfma_f32_16x16x32_bf16(
                                  af[im], bfr[in], acc[im][in], 0, 0, 0);
        if (kt + 1 < NKT) store_tile(cur ^ 1);
        __syncthreads();
    }
    float bias[4];
    #pragma unroll
    for (int in = 0; in < 4; ++in)
        bias[in] = bw[dom * O_SZ + n0 + wc + in * 16 + lr];
    const size_t obase = ((size_t)bz * T_SZ + m0) * O_SZ + n0;
    #pragma unroll
    for (int im = 0; im < 4; ++im) {
        #pragma unroll
        for (int r = 0; r < 4; ++r) {
            const int row = wr + im * 16 + hi * 4 + r;
            float* orow = out + obase + (size_t)row * O_SZ;
            #pragma unroll
            for (int in = 0; in < 4; ++in)
                orow[wc + in * 16 + lr] = acc[im][in][r] + bias[in];
        }
    }
}

extern "C" void kernel_launch(void* const* d_in, const int* in_sizes, int n_in,
                              void* d_out, int out_size, void* d_ws, size_t ws_size,
                              hipStream_t stream) {
    const float* x   = (const float*)d_in[0];
    const int*   dom = (const int*)d_in[1];
    const float* fcw = (const float*)d_in[2];
    const float* bw  = (const float*)d_in[3];
    float* out = (float*)d_out;
    const int B = in_sizes[1];   // 16

    if (ws_size >= WS_NEEDED && B == B_MAX) {
        short* xt = (short*)d_ws;
        short* wt = xt + XT_ELEMS;
        const int chunks = B * 16 * 64 * 512;
        convA<<<chunks / 256, 256, 0, stream>>>(x, xt);
        convB<<<chunks / 256, 256, 0, stream>>>(fcw, dom, wt);
        gemm_128x256<<<dim3(2048), dim3(256), 0, stream>>>(xt, wt, bw, dom, out);
    } else {
        dim3 grid(O_SZ / BN, T_SZ / BM, B);
        dal_gemm<<<grid, dim3(256), 0, stream>>>(x, dom, fcw, bw, out);
    }
}

// Round 15
// 404.040 us; speedup vs baseline: 3.0646x; 1.0344x over previous
//
#include <hip/hip_runtime.h>
#include <hip/hip_bf16.h>
#include <stdint.h>

typedef __attribute__((ext_vector_type(4))) float  f32x4;
typedef __attribute__((ext_vector_type(8))) short  s16x8;
typedef __attribute__((ext_vector_type(4))) short  s16x4;

constexpr int I_SZ = 2048;
constexpr int O_SZ = 2048;
constexpr int T_SZ = 2048;
constexpr int B_MAX = 16;

// pre-tiled layout: per (bz, tile128, ktile32): 8KB block = 8 subtiles x 1KB;
// within a subtile, byte offset l*16 holds the MFMA fragment of lane l:
// row = l&15, k = 4*(l>>4) + {0..3} and 16 + 4*(l>>4) + {0..3}
constexpr size_t XT_ELEMS = (size_t)B_MAX * T_SZ * I_SZ;
constexpr size_t WT_ELEMS = (size_t)B_MAX * I_SZ * O_SZ;
constexpr size_t WS_NEEDED = (XT_ELEMS + WT_ELEMS) * sizeof(short); // 256 MB

__device__ __forceinline__ short f2bf(float f) {
    __hip_bfloat16 h = __float2bfloat16(f);
    return *reinterpret_cast<short*>(&h);
}

__device__ __forceinline__ void gload_lds16(const void* g, void* l) {
    __builtin_amdgcn_global_load_lds(
        (const __attribute__((address_space(1))) unsigned int*)g,
        (__attribute__((address_space(3))) unsigned int*)l, 16, 0, 0);
}

// ---------------- conversion: x fp32 [B][T][I] -> pre-tiled bf16 ----------------
__global__ __launch_bounds__(256) void convA(const float* __restrict__ x,
                                             short* __restrict__ xt) {
    const int c = blockIdx.x * 256 + threadIdx.x;
    const int l  = c & 63;
    const int mi = (c >> 6) & 7;
    const int kt = (c >> 9) & 63;
    const int rest = c >> 15;
    const int mt = rest & 15, bz = rest >> 4;
    const int lr = l & 15, hi = l >> 4;
    const int m = mt * 128 + mi * 16 + lr;
    const float* src = x + ((size_t)(bz * T_SZ + m)) * I_SZ + kt * 32 + 4 * hi;
    f32x4 a = *reinterpret_cast<const f32x4*>(src);
    f32x4 b = *reinterpret_cast<const f32x4*>(src + 16);
    s16x8 h = { f2bf(a[0]), f2bf(a[1]), f2bf(a[2]), f2bf(a[3]),
                f2bf(b[0]), f2bf(b[1]), f2bf(b[2]), f2bf(b[3]) };
    *reinterpret_cast<s16x8*>(xt + (size_t)c * 8) = h;
}

__global__ __launch_bounds__(256) void convB(const float* __restrict__ fcw,
                                             const int* __restrict__ dom_id,
                                             short* __restrict__ wt) {
    const int c = blockIdx.x * 256 + threadIdx.x;
    const int l  = c & 63;
    const int ni = (c >> 6) & 7;
    const int kt = (c >> 9) & 63;
    const int rest = c >> 15;
    const int nt = rest & 15, bz = rest >> 4;
    const int lr = l & 15, hi = l >> 4;
    const int n = nt * 128 + ni * 16 + lr;
    const int dom = dom_id[bz];
    const float* src = fcw + (size_t)dom * ((size_t)I_SZ * O_SZ)
                           + (size_t)(kt * 32 + 4 * hi) * O_SZ + n;
    short h[8];
    #pragma unroll
    for (int j = 0; j < 4; ++j) {
        h[j]     = f2bf(src[(size_t)j * O_SZ]);
        h[4 + j] = f2bf(src[(size_t)(16 + j) * O_SZ]);
    }
    *reinterpret_cast<s16x8*>(wt + (size_t)c * 8) =
        *reinterpret_cast<s16x8*>(h);
}

// ---- bf16 GEMM, 128x256 tile, 4 waves, 2 blocks/CU, ring-3 counted vmcnt ----
// R14 (290us, MfmaUtil 41.5%) proved 2 blocks/CU is the lever. This round moves
// the A-stage off the critical path: ring-3 A buffers + vmcnt(4) BEFORE the
// barrier, so stage(T+1) stays in flight across the barrier and the whole
// compute phase (~2500 cyc to land, was ~0).
// Per-iter FIFO ledger: entry outstanding = stage(T)=4; issue bq(T)=8 then
// stage(T+1)=4 -> 16; vmcnt(4) retires exactly stage(T)+bq(T), leaves
// stage(T+1) flying. Barrier makes buf[T%3] globally visible (each wave waited
// its own vmcnt(4)). WAR: stage(T+1) targets buf[(T+1)%3], last read at iter
// T-2 whose readers passed barrier(T-1) before this issue -> safe.
// Tail: T=31 re-stages identical bytes into its own buffer (same-value write,
// benign). Epilogue drains vmcnt(0).
__global__ __launch_bounds__(256, 2) void gemm_128x256(
        const short* __restrict__ xt, const short* __restrict__ wt,
        const float* __restrict__ bw, const int* __restrict__ dom_id,
        float* __restrict__ out) {
    __shared__ short As[3][8192];   // ring-3 x 16KB (one K64 A-burst, pre-tiled)

    // bijective XCD swizzle: nwg = 2048 = 8 XCDs x 256
    const int bid = blockIdx.x;
    const int swz = (bid & 7) * 256 + (bid >> 3);
    const int bz = swz >> 7;         // 128 blocks per bz
    const int mb = (swz >> 3) & 15;  // 128-row tile index (A panel shared by 8 nb)
    const int nb = swz & 7;          // 256-col tile index

    const int t = threadIdx.x;
    const int wv = t >> 6, l = t & 63;
    const int lr = l & 15, hi = l >> 4;
    const int nti  = wv >> 1;        // which 128-col sub-tile of the 256 N-tile
    const int bsub = (wv & 1) * 4;   // which 4-subtile half within it

    // A: kt innermost in the pre-tiled layout -> a K64 burst is 16KB contiguous
    const short* Abase = xt + (size_t)(bz * 16 + mb) * 64 * 4096;
    // per-lane B fragment base (this wave's exclusive column quarter)
    const short* Bp = wt + (size_t)((bz * 16 + nb * 2 + nti) * 64) * 4096
                         + bsub * 512 + l * 8;

    auto stageA = [&](int buf, int T) {
        #pragma unroll
        for (int r = 0; r < 4; ++r)   // 4 x 4KB rounds (256 thr x 16B), lane-linear
            gload_lds16(Abase + (size_t)(2 * T) * 4096 + r * 2048 + t * 8,
                        &As[buf][r * 2048 + t * 8]);
    };

    f32x4 acc[8][4] = {};

    stageA(0, 0);                    // outstanding = 4 entering iter 0

    for (int T = 0; T < 32; ++T) {
        const int d = T % 3;

        // bq(T) FIRST in the FIFO (8 coalesced 16B/lane loads)
        s16x8 bq0[4], bq1[4];
        {
            const short* b0 = Bp + (size_t)(2 * T) * 4096;
            #pragma unroll
            for (int g = 0; g < 4; ++g)
                bq0[g] = *reinterpret_cast<const s16x8*>(b0 + g * 512);
            #pragma unroll
            for (int g = 0; g < 4; ++g)
                bq1[g] = *reinterpret_cast<const s16x8*>(b0 + 4096 + g * 512);
        }

        // stage(T+1): flies across the barrier + this iter's entire compute
        const int nT = (T + 1 < 32) ? T + 1 : 31;       // tail: same-value rewrite
        stageA((T + 1) % 3, nT);

        // retire stage(T) + bq(T); keep stage(T+1) in flight
        asm volatile("s_waitcnt vmcnt(4)" ::: "memory");
        asm volatile("s_barrier" ::: "memory");          // buf[d] globally ready

        // ks = 0
        s16x8 af[8];
        #pragma unroll
        for (int f = 0; f < 8; ++f)
            af[f] = *reinterpret_cast<const s16x8*>(&As[d][f * 512 + l * 8]);
        __builtin_amdgcn_s_setprio(1);
        #pragma unroll
        for (int f = 0; f < 8; ++f)
            #pragma unroll
            for (int g = 0; g < 4; ++g)
                acc[f][g] = __builtin_amdgcn_mfma_f32_16x16x32_bf16(
                                af[f], bq0[g], acc[f][g], 0, 0, 0);
        __builtin_amdgcn_s_setprio(0);

        // ks = 1
        #pragma unroll
        for (int f = 0; f < 8; ++f)
            af[f] = *reinterpret_cast<const s16x8*>(&As[d][4096 + f * 512 + l * 8]);
        __builtin_amdgcn_s_setprio(1);
        #pragma unroll
        for (int f = 0; f < 8; ++f)
            #pragma unroll
            for (int g = 0; g < 4; ++g)
                acc[f][g] = __builtin_amdgcn_mfma_f32_16x16x32_bf16(
                                af[f], bq1[g], acc[f][g], 0, 0, 0);
        __builtin_amdgcn_s_setprio(0);
    }

    asm volatile("s_waitcnt vmcnt(0)" ::: "memory");     // retire tail stage

    // epilogue: wave tile = rows mb*128..+128, cols nb*256 + wv*64 .. +64
    const int dom = dom_id[bz];
    const int col0 = nb * 256 + wv * 64;
    float bias[4];
    #pragma unroll
    for (int g = 0; g < 4; ++g)
        bias[g] = bw[dom * O_SZ + col0 + g * 16 + lr];

    const size_t obase = ((size_t)bz * T_SZ + mb * 128) * O_SZ + col0;
    #pragma unroll
    for (int f = 0; f < 8; ++f) {
        #pragma unroll
        for (int r = 0; r < 4; ++r) {
            const int row = f * 16 + hi * 4 + r;
            float* orow = out + obase + (size_t)row * O_SZ;
            #pragma unroll
            for (int g = 0; g < 4; ++g)
                orow[g * 16 + lr] = acc[f][g][r] + bias[g];
        }
    }
}

// =============== fallback (round-1 kernel) if workspace is too small ===============
constexpr int BM = 128, BN = 128, BK = 32;
constexpr int LDK = 40;
constexpr int NKT = I_SZ / BK;

__global__ __launch_bounds__(256) void dal_gemm(
    const float* __restrict__ x, const int* __restrict__ dom_id,
    const float* __restrict__ fcw, const float* __restrict__ bw,
    float* __restrict__ out)
{
    __shared__ short As[2][BM * LDK];
    __shared__ short Bs[2][BN * LDK];
    const int bz = blockIdx.z;
    const int m0 = blockIdx.y * BM, n0 = blockIdx.x * BN;
    const int dom = dom_id[bz];
    const float* Ag = x + ((size_t)bz * T_SZ + m0) * I_SZ;
    const float* Wg = fcw + (size_t)dom * ((size_t)I_SZ * O_SZ) + n0;
    const int t = threadIdx.x;
    const int am = t >> 3, ac = (t & 7) << 2;
    const int bk = (t >> 5) << 2, bn = (t & 31) << 2;
    const int wv = t >> 6, lane = t & 63;
    const int wr = (wv >> 1) << 6, wc = (wv & 1) << 6;
    const int hi = lane >> 4, lr = lane & 15;
    f32x4 acc[4][4] = {};
    f32x4 ra[4], rb[4];
    auto load_tile = [&](int kb) {
        #pragma unroll
        for (int p = 0; p < 4; ++p)
            ra[p] = *reinterpret_cast<const f32x4*>(Ag + (size_t)(am + 32 * p) * I_SZ + kb + ac);
        #pragma unroll
        for (int r = 0; r < 4; ++r)
            rb[r] = *reinterpret_cast<const f32x4*>(Wg + (size_t)(kb + bk + r) * O_SZ + bn);
    };
    auto store_tile = [&](int buf) {
        #pragma unroll
        for (int p = 0; p < 4; ++p) {
            s16x4 h = { f2bf(ra[p][0]), f2bf(ra[p][1]), f2bf(ra[p][2]), f2bf(ra[p][3]) };
            *reinterpret_cast<s16x4*>(&As[buf][(am + 32 * p) * LDK + ac]) = h;
        }
        #pragma unroll
        for (int i = 0; i < 4; ++i) {
            s16x4 h = { f2bf(rb[0][i]), f2bf(rb[1][i]), f2bf(rb[2][i]), f2bf(rb[3][i]) };
            *reinterpret_cast<s16x4*>(&Bs[buf][(bn + i) * LDK + bk]) = h;
        }
    };
    load_tile(0);
    store_tile(0);
    __syncthreads();
    for (int kt = 0; kt < NKT; ++kt) {
        const int cur = kt & 1;
        if (kt + 1 < NKT) load_tile((kt + 1) * BK);
        s16x8 af[4], bfr[4];
        #pragma unroll
        for (int im = 0; im < 4; ++im) {
            const short* p = &As[cur][(wr + im * 16 + lr) * LDK + 4 * hi];
            s16x4 lo = *reinterpret_cast<const s16x4*>(p);
            s16x4 hh = *reinterpret_cast<const s16x4*>(p + 16);
            af[im] = __builtin_shufflevector(lo, hh, 0, 1, 2, 3, 4, 5, 6, 7);
        }
        #pragma unroll
        for (int in = 0; in < 4; ++in) {
            const short* p = &Bs[cur][(wc + in * 16 + lr) * LDK + 4 * hi];
            s16x4 lo = *reinterpret_cast<const s16x4*>(p);
            s16x4 hh = *reinterpret_cast<const s16x4*>(p + 16);
            bfr[in] = __builtin_shufflevector(lo, hh, 0, 1, 2, 3, 4, 5, 6, 7);
        }
        #pragma unroll
        for (int im = 0; im < 4; ++im)
            #pragma unroll
            for (int in = 0; in < 4; ++in)
                acc[im][in] = __builtin_amdgcn_mfma_f32_16x16x32_bf16(
                                  af[im], bfr[in], acc[im][in], 0, 0, 0);
        if (kt + 1 < NKT) store_tile(cur ^ 1);
        __syncthreads();
    }
    float bias[4];
    #pragma unroll
    for (int in = 0; in < 4; ++in)
        bias[in] = bw[dom * O_SZ + n0 + wc + in * 16 + lr];
    const size_t obase = ((size_t)bz * T_SZ + m0) * O_SZ + n0;
    #pragma unroll
    for (int im = 0; im < 4; ++im) {
        #pragma unroll
        for (int r = 0; r < 4; ++r) {
            const int row = wr + im * 16 + hi * 4 + r;
            float* orow = out + obase + (size_t)row * O_SZ;
            #pragma unroll
            for (int in = 0; in < 4; ++in)
                orow[wc + in * 16 + lr] = acc[im][in][r] + bias[in];
        }
    }
}

extern "C" void kernel_launch(void* const* d_in, const int* in_sizes, int n_in,
                              void* d_out, int out_size, void* d_ws, size_t ws_size,
                              hipStream_t stream) {
    const float* x   = (const float*)d_in[0];
    const int*   dom = (const int*)d_in[1];
    const float* fcw = (const float*)d_in[2];
    const float* bw  = (const float*)d_in[3];
    float* out = (float*)d_out;
    const int B = in_sizes[1];   // 16

    if (ws_size >= WS_NEEDED && B == B_MAX) {
        short* xt = (short*)d_ws;
        short* wt = xt + XT_ELEMS;
        const int chunks = B * 16 * 64 * 512;
        convA<<<chunks / 256, 256, 0, stream>>>(x, xt);
        convB<<<chunks / 256, 256, 0, stream>>>(fcw, dom, wt);
        gemm_128x256<<<dim3(2048), dim3(256), 0, stream>>>(xt, wt, bw, dom, out);
    } else {
        dim3 grid(O_SZ / BN, T_SZ / BM, B);
        dal_gemm<<<grid, dim3(256), 0, stream>>>(x, dom, fcw, bw, out);
    }
}

// Round 16
// 397.731 us; speedup vs baseline: 3.1132x; 1.0159x over previous
//
#include <hip/hip_runtime.h>
#include <hip/hip_bf16.h>
#include <stdint.h>

typedef __attribute__((ext_vector_type(4))) float  f32x4;
typedef __attribute__((ext_vector_type(8))) short  s16x8;
typedef __attribute__((ext_vector_type(4))) short  s16x4;

constexpr int I_SZ = 2048;
constexpr int O_SZ = 2048;
constexpr int T_SZ = 2048;
constexpr int B_MAX = 16;

// pre-tiled layout: per (bz, tile128, ktile32): 8KB block = 8 subtiles x 1KB;
// within a subtile, byte offset l*16 holds the MFMA fragment of lane l:
// row = l&15, k = 4*(l>>4) + {0..3} and 16 + 4*(l>>4) + {0..3}
constexpr size_t XT_ELEMS = (size_t)B_MAX * T_SZ * I_SZ;
constexpr size_t WT_ELEMS = (size_t)B_MAX * I_SZ * O_SZ;
constexpr size_t WS_NEEDED = (XT_ELEMS + WT_ELEMS) * sizeof(short); // 256 MB

__device__ __forceinline__ short f2bf(float f) {
    __hip_bfloat16 h = __float2bfloat16(f);
    return *reinterpret_cast<short*>(&h);
}

__device__ __forceinline__ void gload_lds16(const void* g, void* l) {
    __builtin_amdgcn_global_load_lds(
        (const __attribute__((address_space(1))) unsigned int*)g,
        (__attribute__((address_space(3))) unsigned int*)l, 16, 0, 0);
}

// ---------------- conversion: x fp32 [B][T][I] -> pre-tiled bf16 ----------------
__global__ __launch_bounds__(256) void convA(const float* __restrict__ x,
                                             short* __restrict__ xt) {
    const int c = blockIdx.x * 256 + threadIdx.x;
    const int l  = c & 63;
    const int mi = (c >> 6) & 7;
    const int kt = (c >> 9) & 63;
    const int rest = c >> 15;
    const int mt = rest & 15, bz = rest >> 4;
    const int lr = l & 15, hi = l >> 4;
    const int m = mt * 128 + mi * 16 + lr;
    const float* src = x + ((size_t)(bz * T_SZ + m)) * I_SZ + kt * 32 + 4 * hi;
    f32x4 a = *reinterpret_cast<const f32x4*>(src);
    f32x4 b = *reinterpret_cast<const f32x4*>(src + 16);
    s16x8 h = { f2bf(a[0]), f2bf(a[1]), f2bf(a[2]), f2bf(a[3]),
                f2bf(b[0]), f2bf(b[1]), f2bf(b[2]), f2bf(b[3]) };
    *reinterpret_cast<s16x8*>(xt + (size_t)c * 8) = h;
}

__global__ __launch_bounds__(256) void convB(const float* __restrict__ fcw,
                                             const int* __restrict__ dom_id,
                                             short* __restrict__ wt) {
    const int c = blockIdx.x * 256 + threadIdx.x;
    const int l  = c & 63;
    const int ni = (c >> 6) & 7;
    const int kt = (c >> 9) & 63;
    const int rest = c >> 15;
    const int nt = rest & 15, bz = rest >> 4;
    const int lr = l & 15, hi = l >> 4;
    const int n = nt * 128 + ni * 16 + lr;
    const int dom = dom_id[bz];
    const float* src = fcw + (size_t)dom * ((size_t)I_SZ * O_SZ)
                           + (size_t)(kt * 32 + 4 * hi) * O_SZ + n;
    short h[8];
    #pragma unroll
    for (int j = 0; j < 4; ++j) {
        h[j]     = f2bf(src[(size_t)j * O_SZ]);
        h[4 + j] = f2bf(src[(size_t)(16 + j) * O_SZ]);
    }
    *reinterpret_cast<s16x8*>(wt + (size_t)c * 8) =
        *reinterpret_cast<s16x8*>(h);
}

// ---- bf16 GEMM, 128x256 tile, 4 waves, 2 blocks/CU, ring-3, B prefetch-ahead ----
// R15 (275us, MfmaUtil 44.8%): A-stage hidden; remaining serial term = bq LLC
// latency exposed at the per-iter vmcnt. Fix (zero extra VGPR): prefetch
// bq(T+1) into the SAME registers right after bq(T)'s consumers (WAR enforced
// by compiler), and move the A-stage to 2-ahead (stage(T+2), ring-3).
// Per-iter issue order: [... compute ks0 ...] bq0(T+1) [... compute ks1 ...]
// bq1(T+1), stage(T+2). FIFO ledger at iter entry: outstanding =
// stage(T)... wait: = stage(T+1)[4 from iter T-1] + bq0(T+1)[4] + bq1(T+1)[4]
// + stage(T+2)[4] = 16; vmcnt(4) retires oldest 12 = stage(T+1)+bq(T+1)
// (needed NOW), leaves stage(T+2) flying ~2 iters. bq issue-to-need ~1200cyc
// >> LLC latency -> hidden. WAR: stage(T+2) targets buf[(T-1)%3], whose
// readers finished before barrier(T) (program order: reads fed iter T-1
// MFMAs); stage issues after barrier(T). Tail: clamped same-value restages,
// epilogue vmcnt(0). Registers: ~104 VGPR + 128 AGPR = 232 <= 256 -> 2
// blocks/CU preserved (R13 lesson).
__global__ __launch_bounds__(256, 2) void gemm_128x256(
        const short* __restrict__ xt, const short* __restrict__ wt,
        const float* __restrict__ bw, const int* __restrict__ dom_id,
        float* __restrict__ out) {
    __shared__ short As[3][8192];   // ring-3 x 16KB (one K64 A-burst, pre-tiled)

    // bijective XCD swizzle: nwg = 2048 = 8 XCDs x 256
    const int bid = blockIdx.x;
    const int swz = (bid & 7) * 256 + (bid >> 3);
    const int bz = swz >> 7;         // 128 blocks per bz
    const int mb = (swz >> 3) & 15;  // 128-row tile index (A panel shared by 8 nb)
    const int nb = swz & 7;          // 256-col tile index

    const int t = threadIdx.x;
    const int wv = t >> 6, l = t & 63;
    const int lr = l & 15, hi = l >> 4;
    const int nti  = wv >> 1;        // which 128-col sub-tile of the 256 N-tile
    const int bsub = (wv & 1) * 4;   // which 4-subtile half within it

    // A: kt innermost in the pre-tiled layout -> a K64 burst is 16KB contiguous
    const short* Abase = xt + (size_t)(bz * 16 + mb) * 64 * 4096;
    // per-lane B fragment base (this wave's exclusive column quarter)
    const short* Bp = wt + (size_t)((bz * 16 + nb * 2 + nti) * 64) * 4096
                         + bsub * 512 + l * 8;

    auto stageA = [&](int buf, int T) {
        #pragma unroll
        for (int r = 0; r < 4; ++r)   // 4 x 4KB rounds (256 thr x 16B), lane-linear
            gload_lds16(Abase + (size_t)(2 * T) * 4096 + r * 2048 + t * 8,
                        &As[buf][r * 2048 + t * 8]);
    };

    f32x4 acc[8][4] = {};
    s16x8 bq0[4], bq1[4];

    auto loadB0 = [&](int T) {
        const short* b0 = Bp + (size_t)(2 * T) * 4096;
        #pragma unroll
        for (int g = 0; g < 4; ++g)
            bq0[g] = *reinterpret_cast<const s16x8*>(b0 + g * 512);
    };
    auto loadB1 = [&](int T) {
        const short* b1 = Bp + (size_t)(2 * T) * 4096 + 4096;
        #pragma unroll
        for (int g = 0; g < 4; ++g)
            bq1[g] = *reinterpret_cast<const s16x8*>(b1 + g * 512);
    };

    // prologue: stage(0), bq(0), stage(1) -> outstanding 16
    stageA(0, 0);
    loadB0(0);
    loadB1(0);
    stageA(1, 1);

    for (int T = 0; T < 32; ++T) {
        const int d = T % 3;
        const int nT = (T + 1 < 32) ? T + 1 : 31;   // tail clamp (same-value)

        // retire stage(T) + bq(T) [oldest 12]; keep stage(T+1) flying
        asm volatile("s_waitcnt vmcnt(4)" ::: "memory");
        asm volatile("s_barrier" ::: "memory");      // buf[d] globally ready

        // ks = 0 (consumes bq0)
        s16x8 af[8];
        #pragma unroll
        for (int f = 0; f < 8; ++f)
            af[f] = *reinterpret_cast<const s16x8*>(&As[d][f * 512 + l * 8]);
        __builtin_amdgcn_s_setprio(1);
        #pragma unroll
        for (int f = 0; f < 8; ++f)
            #pragma unroll
            for (int g = 0; g < 4; ++g)
                acc[f][g] = __builtin_amdgcn_mfma_f32_16x16x32_bf16(
                                af[f], bq0[g], acc[f][g], 0, 0, 0);
        __builtin_amdgcn_s_setprio(0);

        // prefetch bq0(T+1) into the same regs (WAR vs ks0 MFMAs: compiler-held)
        loadB0(nT);

        // ks = 1 (consumes bq1)
        #pragma unroll
        for (int f = 0; f < 8; ++f)
            af[f] = *reinterpret_cast<const s16x8*>(&As[d][4096 + f * 512 + l * 8]);
        __builtin_amdgcn_s_setprio(1);
        #pragma unroll
        for (int f = 0; f < 8; ++f)
            #pragma unroll
            for (int g = 0; g < 4; ++g)
                acc[f][g] = __builtin_amdgcn_mfma_f32_16x16x32_bf16(
                                af[f], bq1[g], acc[f][g], 0, 0, 0);
        __builtin_amdgcn_s_setprio(0);

        // prefetch bq1(T+1); stage A for T+2 (2-ahead, ring-3)
        loadB1(nT);
        stageA((T + 2) % 3, (T + 2 < 32) ? T + 2 : 31);
    }

    asm volatile("s_waitcnt vmcnt(0)" ::: "memory");   // retire tail issues

    // epilogue: wave tile = rows mb*128..+128, cols nb*256 + wv*64 .. +64
    const int dom = dom_id[bz];
    const int col0 = nb * 256 + wv * 64;
    float bias[4];
    #pragma unroll
    for (int g = 0; g < 4; ++g)
        bias[g] = bw[dom * O_SZ + col0 + g * 16 + lr];

    const size_t obase = ((size_t)bz * T_SZ + mb * 128) * O_SZ + col0;
    #pragma unroll
    for (int f = 0; f < 8; ++f) {
        #pragma unroll
        for (int r = 0; r < 4; ++r) {
            const int row = f * 16 + hi * 4 + r;
            float* orow = out + obase + (size_t)row * O_SZ;
            #pragma unroll
            for (int g = 0; g < 4; ++g)
                orow[g * 16 + lr] = acc[f][g][r] + bias[g];
        }
    }
}

// =============== fallback (round-1 kernel) if workspace is too small ===============
constexpr int BM = 128, BN = 128, BK = 32;
constexpr int LDK = 40;
constexpr int NKT = I_SZ / BK;

__global__ __launch_bounds__(256) void dal_gemm(
    const float* __restrict__ x, const int* __restrict__ dom_id,
    const float* __restrict__ fcw, const float* __restrict__ bw,
    float* __restrict__ out)
{
    __shared__ short As[2][BM * LDK];
    __shared__ short Bs[2][BN * LDK];
    const int bz = blockIdx.z;
    const int m0 = blockIdx.y * BM, n0 = blockIdx.x * BN;
    const int dom = dom_id[bz];
    const float* Ag = x + ((size_t)bz * T_SZ + m0) * I_SZ;
    const float* Wg = fcw + (size_t)dom * ((size_t)I_SZ * O_SZ) + n0;
    const int t = threadIdx.x;
    const int am = t >> 3, ac = (t & 7) << 2;
    const int bk = (t >> 5) << 2, bn = (t & 31) << 2;
    const int wv = t >> 6, lane = t & 63;
    const int wr = (wv >> 1) << 6, wc = (wv & 1) << 6;
    const int hi = lane >> 4, lr = lane & 15;
    f32x4 acc[4][4] = {};
    f32x4 ra[4], rb[4];
    auto load_tile = [&](int kb) {
        #pragma unroll
        for (int p = 0; p < 4; ++p)
            ra[p] = *reinterpret_cast<const f32x4*>(Ag + (size_t)(am + 32 * p) * I_SZ + kb + ac);
        #pragma unroll
        for (int r = 0; r < 4; ++r)
            rb[r] = *reinterpret_cast<const f32x4*>(Wg + (size_t)(kb + bk + r) * O_SZ + bn);
    };
    auto store_tile = [&](int buf) {
        #pragma unroll
        for (int p = 0; p < 4; ++p) {
            s16x4 h = { f2bf(ra[p][0]), f2bf(ra[p][1]), f2bf(ra[p][2]), f2bf(ra[p][3]) };
            *reinterpret_cast<s16x4*>(&As[buf][(am + 32 * p) * LDK + ac]) = h;
        }
        #pragma unroll
        for (int i = 0; i < 4; ++i) {
            s16x4 h = { f2bf(rb[0][i]), f2bf(rb[1][i]), f2bf(rb[2][i]), f2bf(rb[3][i]) };
            *reinterpret_cast<s16x4*>(&Bs[buf][(bn + i) * LDK + bk]) = h;
        }
    };
    load_tile(0);
    store_tile(0);
    __syncthreads();
    for (int kt = 0; kt < NKT; ++kt) {
        const int cur = kt & 1;
        if (kt + 1 < NKT) load_tile((kt + 1) * BK);
        s16x8 af[4], bfr[4];
        #pragma unroll
        for (int im = 0; im < 4; ++im) {
            const short* p = &As[cur][(wr + im * 16 + lr) * LDK + 4 * hi];
            s16x4 lo = *reinterpret_cast<const s16x4*>(p);
            s16x4 hh = *reinterpret_cast<const s16x4*>(p + 16);
            af[im] = __builtin_shufflevector(lo, hh, 0, 1, 2, 3, 4, 5, 6, 7);
        }
        #pragma unroll
        for (int in = 0; in < 4; ++in) {
            const short* p = &Bs[cur][(wc + in * 16 + lr) * LDK + 4 * hi];
            s16x4 lo = *reinterpret_cast<const s16x4*>(p);
            s16x4 hh = *reinterpret_cast<const s16x4*>(p + 16);
            bfr[in] = __builtin_shufflevector(lo, hh, 0, 1, 2, 3, 4, 5, 6, 7);
        }
        #pragma unroll
        for (int im = 0; im < 4; ++im)
            #pragma unroll
            for (int in = 0; in < 4; ++in)
                acc[im][in] = __builtin_amdgcn_mfma_f32_16x16x32_bf16(
                                  af[im], bfr[in], acc[im][in], 0, 0, 0);
        if (kt + 1 < NKT) store_tile(cur ^ 1);
        __syncthreads();
    }
    float bias[4];
    #pragma unroll
    for (int in = 0; in < 4; ++in)
        bias[in] = bw[dom * O_SZ + n0 + wc + in * 16 + lr];
    const size_t obase = ((size_t)bz * T_SZ + m0) * O_SZ + n0;
    #pragma unroll
    for (int im = 0; im < 4; ++im) {
        #pragma unroll
        for (int r = 0; r < 4; ++r) {
            const int row = wr + im * 16 + hi * 4 + r;
            float* orow = out + obase + (size_t)row * O_SZ;
            #pragma unroll
            for (int in = 0; in < 4; ++in)
                orow[wc + in * 16 + lr] = acc[im][in][r] + bias[in];
        }
    }
}

extern "C" void kernel_launch(void* const* d_in, const int* in_sizes, int n_in,
                              void* d_out, int out_size, void* d_ws, size_t ws_size,
                              hipStream_t stream) {
    const float* x   = (const float*)d_in[0];
    const int*   dom = (const int*)d_in[1];
    const float* fcw = (const float*)d_in[2];
    const float* bw  = (const float*)d_in[3];
    float* out = (float*)d_out;
    const int B = in_sizes[1];   // 16

    if (ws_size >= WS_NEEDED && B == B_MAX) {
        short* xt = (short*)d_ws;
        short* wt = xt + XT_ELEMS;
        const int chunks = B * 16 * 64 * 512;
        convA<<<chunks / 256, 256, 0, stream>>>(x, xt);
        convB<<<chunks / 256, 256, 0, stream>>>(fcw, dom, wt);
        gemm_128x256<<<dim3(2048), dim3(256), 0, stream>>>(xt, wt, bw, dom, out);
    } else {
        dim3 grid(O_SZ / BN, T_SZ / BM, B);
        dal_gemm<<<grid, dim3(256), 0, stream>>>(x, dom, fcw, bw, out);
    }
}